// Round 1
// baseline (1302.798 us; speedup 1.0000x reference)
//
#include <hip/hip_runtime.h>
#include <hip/hip_bf16.h>
#include <math.h>

// Problem constants
#define D_FEAT 128
#define HC 128      // H*C
#define NHEAD 4
#define CHAN 32
#define NLAYER 3
#define NOUT 64
#define BN_EPS 1e-5f
#define INV_SQRT_C 0.17677669529663687f  // 1/sqrt(32)

// ---------------- CSR build ----------------

__global__ void hist_kernel(const int* __restrict__ dst, int E, int* __restrict__ deg) {
    int e = blockIdx.x * blockDim.x + threadIdx.x;
    if (e < E) atomicAdd(&deg[dst[e]], 1);
}

__global__ __launch_bounds__(1024) void scan_kernel(const int* __restrict__ deg,
                                                    int* __restrict__ rowptr, int n) {
    __shared__ int sdata[1024];
    __shared__ int soff;
    int tid = threadIdx.x;
    if (tid == 0) { soff = 0; rowptr[0] = 0; }
    __syncthreads();
    for (int base = 0; base < n; base += 1024) {
        int i = base + tid;
        int v = (i < n) ? deg[i] : 0;
        sdata[tid] = v;
        __syncthreads();
        for (int s = 1; s < 1024; s <<= 1) {
            int t = (tid >= s) ? sdata[tid - s] : 0;
            __syncthreads();
            sdata[tid] += t;
            __syncthreads();
        }
        if (i < n) rowptr[i + 1] = sdata[tid] + soff;
        __syncthreads();
        if (tid == 0) soff += sdata[1023];
        __syncthreads();
    }
}

__global__ void scatter_kernel(const int* __restrict__ src, const int* __restrict__ dst, int E,
                               const int* __restrict__ rowptr, int* __restrict__ cursor,
                               int* __restrict__ csrsrc) {
    int e = blockIdx.x * blockDim.x + threadIdx.x;
    if (e < E) {
        int d = dst[e];
        int p = atomicAdd(&cursor[d], 1);
        csrsrc[rowptr[d] + p] = src[e];
    }
}

// ---------------- GEMM: C[M x (gridDim.y*64)] = A[M x 128] @ W + bias ----------------
// W selected per column-tile: col tile ct covers C cols [ct*64, ct*64+64); the weight
// matrix used is W{ct>>1} with local col offset (ct&1)*64. ldb = W row stride,
// ldc = C row stride.

__global__ __launch_bounds__(256) void gemm_kernel(
    const float* __restrict__ A, int M,
    const float* __restrict__ W0, const float* __restrict__ W1,
    const float* __restrict__ W2, const float* __restrict__ W3,
    const float* __restrict__ B0, const float* __restrict__ B1,
    const float* __restrict__ B2, const float* __restrict__ B3,
    float* __restrict__ C, int ldb, int ldc)
{
    const int KS = 16;
    int rt = blockIdx.x, ct = blockIdx.y;
    int mat = ct >> 1;
    const float* W    = (mat == 0) ? W0 : (mat == 1) ? W1 : (mat == 2) ? W2 : W3;
    const float* bias = (mat == 0) ? B0 : (mat == 1) ? B1 : (mat == 2) ? B2 : B3;
    int cloc = (ct & 1) * 64;
    int r0 = rt * 64;
    int tid = threadIdx.x;
    int tx = tid & 15, ty = tid >> 4;

    __shared__ float As[64][KS + 1];
    __shared__ float Bs[KS][64];

    float acc[4][4] = {};

    for (int kk = 0; kk < 128; kk += KS) {
        #pragma unroll
        for (int q = 0; q < 4; ++q) {
            int idx = tid + q * 256;
            int ar = idx >> 4;
            int ak = idx & 15;
            int row = r0 + ar;
            As[ar][ak] = (row < M) ? A[(size_t)row * 128 + kk + ak] : 0.f;
        }
        #pragma unroll
        for (int q = 0; q < 4; ++q) {
            int idx = tid + q * 256;
            int bk = idx >> 6;
            int bc = idx & 63;
            Bs[bk][bc] = W[(size_t)(kk + bk) * ldb + cloc + bc];
        }
        __syncthreads();
        #pragma unroll
        for (int k = 0; k < KS; ++k) {
            float a[4], b[4];
            #pragma unroll
            for (int i = 0; i < 4; ++i) a[i] = As[ty + 16 * i][k];
            #pragma unroll
            for (int j = 0; j < 4; ++j) b[j] = Bs[k][tx + 16 * j];
            #pragma unroll
            for (int i = 0; i < 4; ++i)
                #pragma unroll
                for (int j = 0; j < 4; ++j) acc[i][j] += a[i] * b[j];
        }
        __syncthreads();
    }

    #pragma unroll
    for (int j = 0; j < 4; ++j) {
        int c = tx + 16 * j;
        float bv = bias[cloc + c];
        #pragma unroll
        for (int i = 0; i < 4; ++i) {
            int row = r0 + ty + 16 * i;
            if (row < M) C[(size_t)row * ldc + ct * 64 + c] = acc[i][j] + bv;
        }
    }
}

// ---------------- Per-node attention (one wave per node) ----------------
// qkvs row layout per node: [q(128) | k(128) | v(128) | skip(128)]
// Lane owns channels 2*lane, 2*lane+1. Head of lane = lane>>4 (16 lanes per head).

__global__ __launch_bounds__(256) void attn_kernel(
    const float* __restrict__ qkvs,
    const int* __restrict__ rowptr, const int* __restrict__ csrsrc,
    float* __restrict__ scoreb, float* __restrict__ hnext, int N)
{
    int wave = (blockIdx.x * blockDim.x + threadIdx.x) >> 6;
    int lane = threadIdx.x & 63;
    if (wave >= N) return;
    int n = wave;

    float2 q2 = *(const float2*)(qkvs + (size_t)n * 512 + 2 * lane);
    int r0 = rowptr[n], r1 = rowptr[n + 1];

    // Pass 1: scores + online softmax (max, sum)
    float m = -INFINITY, ssum = 0.f;
    bool leader = ((lane & 15) == 0);
    for (int i = r0; i < r1; ++i) {
        int s = csrsrc[i];
        float2 k2 = *(const float2*)(qkvs + (size_t)s * 512 + 128 + 2 * lane);
        float p = q2.x * k2.x + q2.y * k2.y;
        p += __shfl_xor(p, 1);
        p += __shfl_xor(p, 2);
        p += __shfl_xor(p, 4);
        p += __shfl_xor(p, 8);
        float score = p * INV_SQRT_C;
        if (leader) scoreb[(size_t)i * 4 + (lane >> 4)] = score;
        float mnew = fmaxf(m, score);
        ssum = ssum * __expf(m - mnew) + __expf(score - mnew);
        m = mnew;
    }

    // Pass 2: weighted aggregation of v
    float2 acc = make_float2(0.f, 0.f);
    for (int i = r0; i < r1; ++i) {
        int s = csrsrc[i];
        float sc = 0.f;
        if (leader) sc = scoreb[(size_t)i * 4 + (lane >> 4)];  // same lane that wrote it
        sc = __shfl(sc, lane & 48);                            // broadcast from group leader
        float ex = __expf(sc - m);
        float2 v2 = *(const float2*)(qkvs + (size_t)s * 512 + 256 + 2 * lane);
        acc.x += ex * v2.x;
        acc.y += ex * v2.y;
    }

    float inv = (ssum > 0.f) ? 1.0f / ssum : 0.f;
    float2 sk = *(const float2*)(qkvs + (size_t)n * 512 + 384 + 2 * lane);
    float2 o;
    o.x = acc.x * inv + sk.x;
    o.y = acc.y * inv + sk.y;
    *(float2*)(hnext + (size_t)n * 128 + 2 * lane) = o;
}

// ---------------- BatchNorm (training mode: batch mean/biased var) ----------------

__global__ __launch_bounds__(256) void bn_stats_kernel(const float* __restrict__ x, int N, int F,
                                                       float* __restrict__ stats) {
    int tid = threadIdx.x;
    int f = tid & (F - 1);
    int rpb = blockDim.x / F;                 // rows per block-iteration
    int r = blockIdx.x * rpb + (tid / F);
    int rstep = gridDim.x * rpb;
    float s = 0.f, sq = 0.f;
    for (; r < N; r += rstep) {
        float v = x[(size_t)r * F + f];
        s += v;
        sq += v * v;
    }
    __shared__ float ls[256], lq[256];
    ls[tid] = s; lq[tid] = sq;
    __syncthreads();
    if (tid < F) {
        for (int c = F; c < 256; c += F) { s += ls[tid + c]; sq += lq[tid + c]; }
        atomicAdd(&stats[f], s);
        atomicAdd(&stats[512 + f], sq);
    }
}

__global__ void bn_apply_relu_kernel(const float* __restrict__ x, float* __restrict__ y,
                                     const float* __restrict__ stats,
                                     const float* __restrict__ g, const float* __restrict__ b,
                                     int N, int F) {
    float invN = 1.0f / (float)N;
    size_t total = (size_t)N * F;
    for (size_t i = (size_t)blockIdx.x * blockDim.x + threadIdx.x; i < total;
         i += (size_t)gridDim.x * blockDim.x) {
        int f = (int)(i & (size_t)(F - 1));
        float mu = stats[f] * invN;
        float var = stats[512 + f] * invN - mu * mu;
        float sc = rsqrtf(var + BN_EPS) * g[f];
        float v = (x[i] - mu) * sc + b[f];
        y[i] = v > 0.f ? v : 0.f;
    }
}

// ---------------- launch ----------------

extern "C" void kernel_launch(void* const* d_in, const int* in_sizes, int n_in,
                              void* d_out, int out_size, void* d_ws, size_t ws_size,
                              hipStream_t stream) {
    const float* x    = (const float*)d_in[0];
    const int*   edge = (const int*)d_in[1];
    const float* Wq   = (const float*)d_in[2];
    const float* bq   = (const float*)d_in[3];
    const float* Wk   = (const float*)d_in[4];
    const float* bk   = (const float*)d_in[5];
    const float* Wv   = (const float*)d_in[6];
    const float* bv   = (const float*)d_in[7];
    const float* Wsk  = (const float*)d_in[8];
    const float* bsk  = (const float*)d_in[9];
    const float* bng  = (const float*)d_in[10];
    const float* bnb  = (const float*)d_in[11];
    const float* Wo   = (const float*)d_in[12];
    const float* bo   = (const float*)d_in[13];
    const float* bnog = (const float*)d_in[14];
    const float* bnob = (const float*)d_in[15];

    const int N = in_sizes[0] / D_FEAT;
    const int E = in_sizes[1] / 2;
    const int* esrc = edge;
    const int* edst = edge + E;

    char* wsb = (char*)d_ws;
    float* h      = (float*)wsb; wsb += (size_t)N * 128 * 4;
    float* hnext  = (float*)wsb; wsb += (size_t)N * 128 * 4;
    float* qkvs   = (float*)wsb; wsb += (size_t)N * 512 * 4;
    float* scoreb = (float*)wsb; wsb += (size_t)E * 4 * 4;
    float* stats  = (float*)wsb; wsb += 1024 * 4;
    int* rowptr   = (int*)wsb;   wsb += (size_t)(N + 1) * 4;
    int* deg      = (int*)wsb;   wsb += (size_t)N * 4;
    int* csrsrc   = (int*)wsb;   wsb += (size_t)E * 4;

    // ---- CSR build (once; reused by all 3 layers) ----
    hipMemsetAsync(deg, 0, (size_t)N * 4, stream);
    hist_kernel<<<(E + 255) / 256, 256, 0, stream>>>(edst, E, deg);
    scan_kernel<<<1, 1024, 0, stream>>>(deg, rowptr, N);
    hipMemsetAsync(deg, 0, (size_t)N * 4, stream);
    scatter_kernel<<<(E + 255) / 256, 256, 0, stream>>>(esrc, edst, E, rowptr, deg, csrsrc);

    // ---- 3 TransformerConv + BN + ReLU layers ----
    const float* hin = x;
    for (int l = 0; l < NLAYER; ++l) {
        gemm_kernel<<<dim3((N + 63) / 64, 8), 256, 0, stream>>>(
            hin, N,
            Wq + (size_t)l * 16384, Wk + (size_t)l * 16384,
            Wv + (size_t)l * 16384, Wsk + (size_t)l * 16384,
            bq + l * 128, bk + l * 128, bv + l * 128, bsk + l * 128,
            qkvs, 128, 512);
        attn_kernel<<<(N + 3) / 4, 256, 0, stream>>>(qkvs, rowptr, csrsrc, scoreb, hnext, N);
        hipMemsetAsync(stats, 0, 1024 * 4, stream);
        bn_stats_kernel<<<256, 256, 0, stream>>>(hnext, N, 128, stats);
        bn_apply_relu_kernel<<<2048, 256, 0, stream>>>(hnext, h, stats,
                                                       bng + l * 128, bnb + l * 128, N, 128);
        hin = h;
    }

    // ---- Final projection + BN + ReLU ----
    float* outpre = qkvs;  // qkvs region is free now
    gemm_kernel<<<dim3((N + 63) / 64, 1), 256, 0, stream>>>(
        h, N, Wo, Wo, Wo, Wo, bo, bo, bo, bo, outpre, 64, 64);
    hipMemsetAsync(stats, 0, 1024 * 4, stream);
    bn_stats_kernel<<<256, 256, 0, stream>>>(outpre, N, 64, stats);
    bn_apply_relu_kernel<<<2048, 256, 0, stream>>>(outpre, (float*)d_out, stats,
                                                   bnog, bnob, N, 64);
}

// Round 2
// 757.069 us; speedup vs baseline: 1.7208x; 1.7208x over previous
//
#include <hip/hip_runtime.h>
#include <hip/hip_bf16.h>
#include <math.h>

#define D_FEAT 128
#define NLAYER 3
#define BN_EPS 1e-5f
#define INV_SQRT_C 0.17677669529663687f  // 1/sqrt(32)

typedef __bf16 bf16x8 __attribute__((ext_vector_type(8)));
typedef float f32x4 __attribute__((ext_vector_type(4)));

static __device__ __forceinline__ unsigned short f2bf(float f) {
    return __builtin_bit_cast(unsigned short, __float2bfloat16(f));
}

// ---------------- conversions ----------------

__global__ void cvt_bf16_kernel(const float* __restrict__ src, unsigned short* __restrict__ dst,
                                size_t n4) {
    for (size_t t = (size_t)blockIdx.x * blockDim.x + threadIdx.x; t < n4;
         t += (size_t)gridDim.x * blockDim.x) {
        size_t i = t * 4;
        float4 v = *(const float4*)(src + i);
        ushort4 u;
        u.x = f2bf(v.x); u.y = f2bf(v.y); u.z = f2bf(v.z); u.w = f2bf(v.w);
        *(ushort4*)(dst + i) = u;
    }
}

// dst[l][n][k] = bf16(src[l][k][n])
__global__ void transp_cvt_kernel(const float* __restrict__ src, unsigned short* __restrict__ dst,
                                  int L, int lsrc, int ldst, int K, int Ncols) {
    int total = L * K * Ncols;
    for (int i = blockIdx.x * blockDim.x + threadIdx.x; i < total;
         i += gridDim.x * blockDim.x) {
        int l = i / (K * Ncols);
        int rem = i - l * (K * Ncols);
        int k = rem / Ncols;
        int nn = rem - k * Ncols;
        dst[(size_t)l * ldst + (size_t)nn * K + k] =
            f2bf(src[(size_t)l * lsrc + (size_t)k * Ncols + nn]);
    }
}

// ---------------- CSR build ----------------

__global__ void hist_kernel(const int* __restrict__ dst, int E, int* __restrict__ deg) {
    int e = blockIdx.x * blockDim.x + threadIdx.x;
    if (e < E) atomicAdd(&deg[dst[e]], 1);
}

// block-local inclusive scan over 1024 elements (4/thread, 256 threads)
__global__ __launch_bounds__(256) void scan1_kernel(const int* __restrict__ deg, int n,
                                                    int* __restrict__ rowptr,
                                                    int* __restrict__ partials) {
    int b = blockIdx.x, tid = threadIdx.x;
    int base = b * 1024 + tid * 4;
    int4 d = {0, 0, 0, 0};
    if (base + 3 < n) d = *(const int4*)(deg + base);
    else {
        if (base + 0 < n) d.x = deg[base + 0];
        if (base + 1 < n) d.y = deg[base + 1];
        if (base + 2 < n) d.z = deg[base + 2];
        if (base + 3 < n) d.w = deg[base + 3];
    }
    int p0 = d.x, p1 = p0 + d.y, p2 = p1 + d.z, p3 = p2 + d.w;
    int v = p3;
    int lane = tid & 63;
    #pragma unroll
    for (int off = 1; off < 64; off <<= 1) {
        int t = __shfl_up(v, off);
        if (lane >= off) v += t;
    }
    __shared__ int wsum[4];
    int w = tid >> 6;
    if (lane == 63) wsum[w] = v;
    __syncthreads();
    int woff = 0;
    #pragma unroll
    for (int j = 0; j < 4; ++j) if (j < w) woff += wsum[j];
    int excl = woff + v - p3;
    if (base + 0 < n) rowptr[base + 1] = excl + p0;
    if (base + 1 < n) rowptr[base + 2] = excl + p1;
    if (base + 2 < n) rowptr[base + 3] = excl + p2;
    if (base + 3 < n) rowptr[base + 4] = excl + p3;
    if (tid == 255) partials[b] = excl + p3;
    if (b == 0 && tid == 0) rowptr[0] = 0;
}

__global__ void scan2_kernel(int* __restrict__ partials, int nb) {
    int lane = threadIdx.x;
    int v = (lane < nb) ? partials[lane] : 0;
    #pragma unroll
    for (int off = 1; off < 64; off <<= 1) {
        int t = __shfl_up(v, off);
        if (lane >= off) v += t;
    }
    if (lane < nb) partials[lane] = v;  // inclusive
}

__global__ __launch_bounds__(256) void scan3_kernel(int* __restrict__ rowptr, int n,
                                                    const int* __restrict__ partials) {
    int b = blockIdx.x, tid = threadIdx.x;
    if (b == 0) return;
    int off = partials[b - 1];
    int base = b * 1024 + tid * 4;
    #pragma unroll
    for (int j = 0; j < 4; ++j) {
        int i = base + j;
        if (i < n) rowptr[i + 1] += off;
    }
}

__global__ void scatter_kernel(const int* __restrict__ src, const int* __restrict__ dst, int E,
                               const int* __restrict__ rowptr, int* __restrict__ cursor,
                               int* __restrict__ csrsrc) {
    int e = blockIdx.x * blockDim.x + threadIdx.x;
    if (e < E) {
        int d = dst[e];
        int p = atomicAdd(&cursor[d], 1);
        csrsrc[rowptr[d] + p] = src[e];
    }
}

// ---------------- MFMA GEMM: out = A[M x 128] @ W + bias ----------------
// A: bf16 [M][128]; Wt: bf16 [4][128(n)][128(k)] (pre-transposed); ct picks output.
// Block tile 128x128, BK=64, 4 waves (2x2), wave tile 64x64.

#define LDSS 72  // shorts per LDS row (64 data + 8 pad = 144 B, 16B-aligned, conflict-free)

__global__ __launch_bounds__(256) void gemm_qkvs_kernel(
    const unsigned short* __restrict__ A, int M,
    const unsigned short* __restrict__ Wt,
    const float* __restrict__ b0, const float* __restrict__ b1,
    const float* __restrict__ b2, const float* __restrict__ b3,
    float* __restrict__ q, unsigned short* __restrict__ kb,
    unsigned short* __restrict__ vb, float* __restrict__ s)
{
    __shared__ unsigned short As[128 * LDSS];
    __shared__ unsigned short Bs[128 * LDSS];
    int rt = blockIdx.x, ct = blockIdx.y;
    int r0 = rt * 128;
    const unsigned short* W = Wt + (size_t)ct * 16384;
    const float* bias = (ct == 0) ? b0 : (ct == 1) ? b1 : (ct == 2) ? b2 : b3;
    int tid = threadIdx.x;
    int wid = tid >> 6, lane = tid & 63;
    int wm = wid >> 1, wn = wid & 1;
    int lr = lane & 15, lk = lane >> 4;

    f32x4 acc[4][4] = {};

    for (int kk = 0; kk < 128; kk += 64) {
        int row = tid >> 3;
        int c8 = (tid & 7) * 8;
        #pragma unroll
        for (int it = 0; it < 4; ++it) {
            int rr = row + it * 32;
            int gr = r0 + rr;
            int4 val = {0, 0, 0, 0};
            if (gr < M) val = *(const int4*)(A + (size_t)gr * 128 + kk + c8);
            *(int4*)(&As[rr * LDSS + c8]) = val;
        }
        #pragma unroll
        for (int it = 0; it < 4; ++it) {
            int rr = row + it * 32;
            int4 val = *(const int4*)(W + (size_t)rr * 128 + kk + c8);
            *(int4*)(&Bs[rr * LDSS + c8]) = val;
        }
        __syncthreads();

        bf16x8 a[4][2], b[4][2];
        #pragma unroll
        for (int mi = 0; mi < 4; ++mi)
            #pragma unroll
            for (int ks = 0; ks < 2; ++ks)
                a[mi][ks] = *(const bf16x8*)(&As[(wm * 64 + mi * 16 + lr) * LDSS + ks * 32 + lk * 8]);
        #pragma unroll
        for (int nj = 0; nj < 4; ++nj)
            #pragma unroll
            for (int ks = 0; ks < 2; ++ks)
                b[nj][ks] = *(const bf16x8*)(&Bs[(wn * 64 + nj * 16 + lr) * LDSS + ks * 32 + lk * 8]);
        #pragma unroll
        for (int ks = 0; ks < 2; ++ks)
            #pragma unroll
            for (int mi = 0; mi < 4; ++mi)
                #pragma unroll
                for (int nj = 0; nj < 4; ++nj)
                    acc[mi][nj] = __builtin_amdgcn_mfma_f32_16x16x32_bf16(
                        a[mi][ks], b[nj][ks], acc[mi][nj], 0, 0, 0);
        __syncthreads();
    }

    #pragma unroll
    for (int mi = 0; mi < 4; ++mi) {
        #pragma unroll
        for (int nj = 0; nj < 4; ++nj) {
            int col = wn * 64 + nj * 16 + lr;
            float bv = bias[col];
            #pragma unroll
            for (int reg = 0; reg < 4; ++reg) {
                int rw = r0 + wm * 64 + mi * 16 + lk * 4 + reg;
                if (rw < M) {
                    float val = acc[mi][nj][reg] + bv;
                    size_t off = (size_t)rw * 128 + col;
                    if (ct == 0) q[off] = val;
                    else if (ct == 1) kb[off] = f2bf(val);
                    else if (ct == 2) vb[off] = f2bf(val);
                    else s[off] = val;
                }
            }
        }
    }
}

// Final: out[M x 64] = A[M x 128] @ Wo + bo.  Wot bf16 [64(n)][128(k)].
__global__ __launch_bounds__(256) void gemm_final_kernel(
    const unsigned short* __restrict__ A, int M,
    const unsigned short* __restrict__ Wot, const float* __restrict__ bias,
    float* __restrict__ out)
{
    __shared__ unsigned short As[128 * LDSS];
    __shared__ unsigned short Bs[64 * LDSS];
    int r0 = blockIdx.x * 128;
    int tid = threadIdx.x;
    int wid = tid >> 6, lane = tid & 63;
    int wm = wid >> 1, wn = wid & 1;
    int lr = lane & 15, lk = lane >> 4;

    f32x4 acc[4][2] = {};

    for (int kk = 0; kk < 128; kk += 64) {
        int row = tid >> 3;
        int c8 = (tid & 7) * 8;
        #pragma unroll
        for (int it = 0; it < 4; ++it) {
            int rr = row + it * 32;
            int gr = r0 + rr;
            int4 val = {0, 0, 0, 0};
            if (gr < M) val = *(const int4*)(A + (size_t)gr * 128 + kk + c8);
            *(int4*)(&As[rr * LDSS + c8]) = val;
        }
        #pragma unroll
        for (int it = 0; it < 2; ++it) {
            int rr = row + it * 32;
            int4 val = *(const int4*)(Wot + (size_t)rr * 128 + kk + c8);
            *(int4*)(&Bs[rr * LDSS + c8]) = val;
        }
        __syncthreads();

        bf16x8 a[4][2], b[2][2];
        #pragma unroll
        for (int mi = 0; mi < 4; ++mi)
            #pragma unroll
            for (int ks = 0; ks < 2; ++ks)
                a[mi][ks] = *(const bf16x8*)(&As[(wm * 64 + mi * 16 + lr) * LDSS + ks * 32 + lk * 8]);
        #pragma unroll
        for (int nj = 0; nj < 2; ++nj)
            #pragma unroll
            for (int ks = 0; ks < 2; ++ks)
                b[nj][ks] = *(const bf16x8*)(&Bs[(wn * 32 + nj * 16 + lr) * LDSS + ks * 32 + lk * 8]);
        #pragma unroll
        for (int ks = 0; ks < 2; ++ks)
            #pragma unroll
            for (int mi = 0; mi < 4; ++mi)
                #pragma unroll
                for (int nj = 0; nj < 2; ++nj)
                    acc[mi][nj] = __builtin_amdgcn_mfma_f32_16x16x32_bf16(
                        a[mi][ks], b[nj][ks], acc[mi][nj], 0, 0, 0);
        __syncthreads();
    }

    #pragma unroll
    for (int mi = 0; mi < 4; ++mi) {
        #pragma unroll
        for (int nj = 0; nj < 2; ++nj) {
            int col = wn * 32 + nj * 16 + lr;
            float bv = bias[col];
            #pragma unroll
            for (int reg = 0; reg < 4; ++reg) {
                int rw = r0 + wm * 64 + mi * 16 + lk * 4 + reg;
                if (rw < M) out[(size_t)rw * 64 + col] = acc[mi][nj][reg] + bv;
            }
        }
    }
}

// ---------------- Per-node attention (one wave per node) ----------------

__global__ __launch_bounds__(256) void attn_kernel(
    const float* __restrict__ q, const unsigned short* __restrict__ kb,
    const unsigned short* __restrict__ vb, const float* __restrict__ sk,
    const int* __restrict__ rowptr, const int* __restrict__ csrsrc,
    float* __restrict__ scoreb, float* __restrict__ hnext, int N)
{
    int n = (blockIdx.x * blockDim.x + threadIdx.x) >> 6;
    int lane = threadIdx.x & 63;
    if (n >= N) return;

    float2 q2 = *(const float2*)(q + (size_t)n * 128 + 2 * lane);
    int r0 = rowptr[n], r1 = rowptr[n + 1];
    int h = lane >> 4;
    bool leader = ((lane & 15) == 0);

    float m = -INFINITY, ssum = 0.f;
    int i = r0;
    for (; i + 2 <= r1; i += 2) {
        int s0 = csrsrc[i], s1 = csrsrc[i + 1];
        unsigned u0 = *(const unsigned*)(kb + (size_t)s0 * 128 + 2 * lane);
        unsigned u1 = *(const unsigned*)(kb + (size_t)s1 * 128 + 2 * lane);
        float p0 = q2.x * __uint_as_float(u0 << 16) + q2.y * __uint_as_float(u0 & 0xffff0000u);
        float p1 = q2.x * __uint_as_float(u1 << 16) + q2.y * __uint_as_float(u1 & 0xffff0000u);
        p0 += __shfl_xor(p0, 1); p1 += __shfl_xor(p1, 1);
        p0 += __shfl_xor(p0, 2); p1 += __shfl_xor(p1, 2);
        p0 += __shfl_xor(p0, 4); p1 += __shfl_xor(p1, 4);
        p0 += __shfl_xor(p0, 8); p1 += __shfl_xor(p1, 8);
        float sc0 = p0 * INV_SQRT_C, sc1 = p1 * INV_SQRT_C;
        if (leader) {
            scoreb[(size_t)i * 4 + h] = sc0;
            scoreb[(size_t)(i + 1) * 4 + h] = sc1;
        }
        float mnew = fmaxf(m, fmaxf(sc0, sc1));
        ssum = ssum * __expf(m - mnew) + __expf(sc0 - mnew) + __expf(sc1 - mnew);
        m = mnew;
    }
    for (; i < r1; ++i) {
        int s0 = csrsrc[i];
        unsigned u0 = *(const unsigned*)(kb + (size_t)s0 * 128 + 2 * lane);
        float p0 = q2.x * __uint_as_float(u0 << 16) + q2.y * __uint_as_float(u0 & 0xffff0000u);
        p0 += __shfl_xor(p0, 1);
        p0 += __shfl_xor(p0, 2);
        p0 += __shfl_xor(p0, 4);
        p0 += __shfl_xor(p0, 8);
        float sc0 = p0 * INV_SQRT_C;
        if (leader) scoreb[(size_t)i * 4 + h] = sc0;
        float mnew = fmaxf(m, sc0);
        ssum = ssum * __expf(m - mnew) + __expf(sc0 - mnew);
        m = mnew;
    }

    float2 acc0 = make_float2(0.f, 0.f), acc1 = make_float2(0.f, 0.f);
    i = r0;
    for (; i + 2 <= r1; i += 2) {
        int s0 = csrsrc[i], s1 = csrsrc[i + 1];
        float sc0 = 0.f, sc1 = 0.f;
        if (leader) {
            sc0 = scoreb[(size_t)i * 4 + h];
            sc1 = scoreb[(size_t)(i + 1) * 4 + h];
        }
        sc0 = __shfl(sc0, lane & 48);
        sc1 = __shfl(sc1, lane & 48);
        unsigned u0 = *(const unsigned*)(vb + (size_t)s0 * 128 + 2 * lane);
        unsigned u1 = *(const unsigned*)(vb + (size_t)s1 * 128 + 2 * lane);
        float e0 = __expf(sc0 - m), e1 = __expf(sc1 - m);
        acc0.x += e0 * __uint_as_float(u0 << 16);
        acc0.y += e0 * __uint_as_float(u0 & 0xffff0000u);
        acc1.x += e1 * __uint_as_float(u1 << 16);
        acc1.y += e1 * __uint_as_float(u1 & 0xffff0000u);
    }
    for (; i < r1; ++i) {
        int s0 = csrsrc[i];
        float sc0 = 0.f;
        if (leader) sc0 = scoreb[(size_t)i * 4 + h];
        sc0 = __shfl(sc0, lane & 48);
        unsigned u0 = *(const unsigned*)(vb + (size_t)s0 * 128 + 2 * lane);
        float e0 = __expf(sc0 - m);
        acc0.x += e0 * __uint_as_float(u0 << 16);
        acc0.y += e0 * __uint_as_float(u0 & 0xffff0000u);
    }

    float inv = (ssum > 0.f) ? 1.0f / ssum : 0.f;
    float2 skv = *(const float2*)(sk + (size_t)n * 128 + 2 * lane);
    float2 o;
    o.x = (acc0.x + acc1.x) * inv + skv.x;
    o.y = (acc0.y + acc1.y) * inv + skv.y;
    *(float2*)(hnext + (size_t)n * 128 + 2 * lane) = o;
}

// ---------------- BatchNorm ----------------

__global__ __launch_bounds__(256) void bn_stats_kernel(const float* __restrict__ x, int N, int F,
                                                       float* __restrict__ stats) {
    int tid = threadIdx.x;
    int F4 = F >> 2;
    int c4 = tid & (F4 - 1);
    int rpi = 256 / F4;
    int r = blockIdx.x * rpi + (tid / F4);
    int rstep = gridDim.x * rpi;
    float sx = 0, sy = 0, sz = 0, sw = 0, qx = 0, qy = 0, qz = 0, qw = 0;
    for (; r < N; r += rstep) {
        float4 v = *(const float4*)(x + (size_t)r * F + c4 * 4);
        sx += v.x; sy += v.y; sz += v.z; sw += v.w;
        qx += v.x * v.x; qy += v.y * v.y; qz += v.z * v.z; qw += v.w * v.w;
    }
    __shared__ float4 ls[256], lq[256];
    ls[tid] = make_float4(sx, sy, sz, sw);
    lq[tid] = make_float4(qx, qy, qz, qw);
    __syncthreads();
    if (tid < F4) {
        for (int c = F4; c < 256; c += F4) {
            float4 a = ls[tid + c], b = lq[tid + c];
            sx += a.x; sy += a.y; sz += a.z; sw += a.w;
            qx += b.x; qy += b.y; qz += b.z; qw += b.w;
        }
        atomicAdd(&stats[tid * 4 + 0], sx);
        atomicAdd(&stats[tid * 4 + 1], sy);
        atomicAdd(&stats[tid * 4 + 2], sz);
        atomicAdd(&stats[tid * 4 + 3], sw);
        atomicAdd(&stats[512 + tid * 4 + 0], qx);
        atomicAdd(&stats[512 + tid * 4 + 1], qy);
        atomicAdd(&stats[512 + tid * 4 + 2], qz);
        atomicAdd(&stats[512 + tid * 4 + 3], qw);
    }
}

__global__ void bn_finalize_kernel(float* __restrict__ stats, const float* __restrict__ g,
                                   const float* __restrict__ b, int N, int F) {
    int f = threadIdx.x;
    if (f < F) {
        float invN = 1.0f / (float)N;
        float mu = stats[f] * invN;
        float var = stats[512 + f] * invN - mu * mu;
        float sc = rsqrtf(var + BN_EPS) * g[f];
        stats[256 + f] = sc;
        stats[768 + f] = b[f] - mu * sc;
    }
}

__global__ void bn_apply_bf16_kernel(const float* __restrict__ x, unsigned short* __restrict__ y,
                                     const float* __restrict__ stats, int N, int F) {
    const float* scale = stats + 256;
    const float* shift = stats + 768;
    size_t total4 = (size_t)N * F >> 2;
    int Fm = F - 1;
    for (size_t t = (size_t)blockIdx.x * blockDim.x + threadIdx.x; t < total4;
         t += (size_t)gridDim.x * blockDim.x) {
        size_t i = t * 4;
        int f = (int)(i & (size_t)Fm);
        float4 v = *(const float4*)(x + i);
        float r0 = fmaxf(v.x * scale[f + 0] + shift[f + 0], 0.f);
        float r1 = fmaxf(v.y * scale[f + 1] + shift[f + 1], 0.f);
        float r2 = fmaxf(v.z * scale[f + 2] + shift[f + 2], 0.f);
        float r3 = fmaxf(v.w * scale[f + 3] + shift[f + 3], 0.f);
        ushort4 u;
        u.x = f2bf(r0); u.y = f2bf(r1); u.z = f2bf(r2); u.w = f2bf(r3);
        *(ushort4*)(y + i) = u;
    }
}

__global__ void bn_apply_f32_kernel(const float* __restrict__ x, float* __restrict__ y,
                                    const float* __restrict__ stats, int N, int F) {
    const float* scale = stats + 256;
    const float* shift = stats + 768;
    size_t total4 = (size_t)N * F >> 2;
    int Fm = F - 1;
    for (size_t t = (size_t)blockIdx.x * blockDim.x + threadIdx.x; t < total4;
         t += (size_t)gridDim.x * blockDim.x) {
        size_t i = t * 4;
        int f = (int)(i & (size_t)Fm);
        float4 v = *(const float4*)(x + i);
        float4 o;
        o.x = fmaxf(v.x * scale[f + 0] + shift[f + 0], 0.f);
        o.y = fmaxf(v.y * scale[f + 1] + shift[f + 1], 0.f);
        o.z = fmaxf(v.z * scale[f + 2] + shift[f + 2], 0.f);
        o.w = fmaxf(v.w * scale[f + 3] + shift[f + 3], 0.f);
        *(float4*)(y + i) = o;
    }
}

// ---------------- launch ----------------

static inline size_t al16(size_t x) { return (x + 15) & ~(size_t)15; }

extern "C" void kernel_launch(void* const* d_in, const int* in_sizes, int n_in,
                              void* d_out, int out_size, void* d_ws, size_t ws_size,
                              hipStream_t stream) {
    const float* x    = (const float*)d_in[0];
    const int*   edge = (const int*)d_in[1];
    const float* Wq   = (const float*)d_in[2];
    const float* bq   = (const float*)d_in[3];
    const float* Wk   = (const float*)d_in[4];
    const float* bk   = (const float*)d_in[5];
    const float* Wv   = (const float*)d_in[6];
    const float* bv   = (const float*)d_in[7];
    const float* Wsk  = (const float*)d_in[8];
    const float* bsk  = (const float*)d_in[9];
    const float* bng  = (const float*)d_in[10];
    const float* bnb  = (const float*)d_in[11];
    const float* Wo   = (const float*)d_in[12];
    const float* bo   = (const float*)d_in[13];
    const float* bnog = (const float*)d_in[14];
    const float* bnob = (const float*)d_in[15];

    const int N = in_sizes[0] / D_FEAT;
    const int E = in_sizes[1] / 2;
    const int* esrc = edge;
    const int* edst = edge + E;

    char* wsb = (char*)d_ws;
    unsigned short* xb = (unsigned short*)wsb; wsb += al16((size_t)N * 128 * 2);
    unsigned short* hb = (unsigned short*)wsb; wsb += al16((size_t)N * 128 * 2);
    unsigned short* kb = (unsigned short*)wsb; wsb += al16((size_t)N * 128 * 2);
    unsigned short* vb = (unsigned short*)wsb; wsb += al16((size_t)N * 128 * 2);
    float* q      = (float*)wsb; wsb += al16((size_t)N * 128 * 4);
    float* s      = (float*)wsb; wsb += al16((size_t)N * 128 * 4);
    float* hnext  = (float*)wsb; wsb += al16((size_t)N * 128 * 4);
    float* outpre = (float*)wsb; wsb += al16((size_t)N * 64 * 4);
    float* scoreb = (float*)wsb; wsb += al16((size_t)E * 4 * 4);
    unsigned short* Wt  = (unsigned short*)wsb; wsb += al16((size_t)NLAYER * 4 * 16384 * 2);
    unsigned short* Wot = (unsigned short*)wsb; wsb += al16((size_t)64 * 128 * 2);
    float* stats  = (float*)wsb; wsb += al16(1024 * 4);
    int* rowptr   = (int*)wsb;   wsb += al16((size_t)(N + 1) * 4);
    int* deg      = (int*)wsb;   wsb += al16((size_t)N * 4);
    int* csrsrc   = (int*)wsb;   wsb += al16((size_t)E * 4);
    int* partials = (int*)wsb;   wsb += al16(256 * 4);

    // conversions
    cvt_bf16_kernel<<<2048, 256, 0, stream>>>(x, xb, (size_t)N * 128 / 4);
    transp_cvt_kernel<<<256, 256, 0, stream>>>(Wq,  Wt + 0 * 16384, NLAYER, 16384, 4 * 16384, 128, 128);
    transp_cvt_kernel<<<256, 256, 0, stream>>>(Wk,  Wt + 1 * 16384, NLAYER, 16384, 4 * 16384, 128, 128);
    transp_cvt_kernel<<<256, 256, 0, stream>>>(Wv,  Wt + 2 * 16384, NLAYER, 16384, 4 * 16384, 128, 128);
    transp_cvt_kernel<<<256, 256, 0, stream>>>(Wsk, Wt + 3 * 16384, NLAYER, 16384, 4 * 16384, 128, 128);
    transp_cvt_kernel<<<64, 256, 0, stream>>>(Wo, Wot, 1, 8192, 8192, 128, 64);

    // CSR build
    const int nb1 = (N + 1023) / 1024;
    hipMemsetAsync(deg, 0, (size_t)N * 4, stream);
    hist_kernel<<<(E + 255) / 256, 256, 0, stream>>>(edst, E, deg);
    scan1_kernel<<<nb1, 256, 0, stream>>>(deg, N, rowptr, partials);
    scan2_kernel<<<1, 64, 0, stream>>>(partials, nb1);
    scan3_kernel<<<nb1, 256, 0, stream>>>(rowptr, N, partials);
    hipMemsetAsync(deg, 0, (size_t)N * 4, stream);
    scatter_kernel<<<(E + 255) / 256, 256, 0, stream>>>(esrc, edst, E, rowptr, deg, csrsrc);

    const int gemm_rb = (N + 127) / 128;
    const unsigned short* hin = xb;
    for (int l = 0; l < NLAYER; ++l) {
        gemm_qkvs_kernel<<<dim3(gemm_rb, 4), 256, 0, stream>>>(
            hin, N, Wt + (size_t)l * 4 * 16384,
            bq + l * 128, bk + l * 128, bv + l * 128, bsk + l * 128,
            q, kb, vb, s);
        attn_kernel<<<(N + 3) / 4, 256, 0, stream>>>(q, kb, vb, s, rowptr, csrsrc,
                                                     scoreb, hnext, N);
        hipMemsetAsync(stats, 0, 1024 * 4, stream);
        bn_stats_kernel<<<256, 256, 0, stream>>>(hnext, N, 128, stats);
        bn_finalize_kernel<<<1, 128, 0, stream>>>(stats, bng + l * 128, bnb + l * 128, N, 128);
        bn_apply_bf16_kernel<<<2048, 256, 0, stream>>>(hnext, hb, stats, N, 128);
        hin = hb;
    }

    gemm_final_kernel<<<gemm_rb, 256, 0, stream>>>(hb, N, Wot, bo, outpre);
    hipMemsetAsync(stats, 0, 1024 * 4, stream);
    bn_stats_kernel<<<256, 256, 0, stream>>>(outpre, N, 64, stats);
    bn_finalize_kernel<<<1, 128, 0, stream>>>(stats, bnog, bnob, N, 64);
    bn_apply_f32_kernel<<<2048, 256, 0, stream>>>(outpre, (float*)d_out, stats, N, 64);
}